// Round 1
// baseline (2236.734 us; speedup 1.0000x reference)
//
#include <hip/hip_runtime.h>
#include <hip/hip_bf16.h>
#include <hip/hip_fp16.h>

#define L_ATOMS 2048
#define N_TOK 512
#define CA 128
#define CP 16
#define CT 384
#define NBLK 3
#define NHEAD 4
#define HDIM 32
#define FFD 512
#define F1D 388

typedef _Float16 half8 __attribute__((ext_vector_type(8)));
typedef float f32x4 __attribute__((ext_vector_type(4)));

__device__ __forceinline__ float grp16_max(float v) {
  v = fmaxf(v, __shfl_xor(v, 1));
  v = fmaxf(v, __shfl_xor(v, 2));
  v = fmaxf(v, __shfl_xor(v, 4));
  v = fmaxf(v, __shfl_xor(v, 8));
  return v;
}
__device__ __forceinline__ float grp16_sum(float v) {
  v += __shfl_xor(v, 1);
  v += __shfl_xor(v, 2);
  v += __shfl_xor(v, 4);
  v += __shfl_xor(v, 8);
  return v;
}

// ---------------------------------------------------------------------------
// C_L = feat @ W_in ; Q init = C_L ; csl = relu(C_L)@W_sl ; csm = relu(C_L)@W_sm
// 8 atoms per block, 256 threads.
__global__ __launch_bounds__(256) void k_cl(
    const float* __restrict__ pos, const float* __restrict__ charge,
    const float* __restrict__ elem, const float* __restrict__ chars,
    const float* __restrict__ W_in, const float* __restrict__ W_sl,
    const float* __restrict__ W_sm,
    float* __restrict__ out_cl, float* __restrict__ out_q,
    float* __restrict__ csl, float* __restrict__ csm) {
  __shared__ float feat_s[8][F1D];
  __shared__ float rcl_s[8][CA];
  const int t = threadIdx.x;
  const int l0 = blockIdx.x * 8;
  if (t < 24) feat_s[t / 3][t % 3] = pos[l0 * 3 + t];
  else if (t < 32) feat_s[t - 24][3] = charge[l0 + t - 24];
  for (int k = 0; k < 4; k++) {
    int idx = t + k * 256;
    feat_s[idx >> 7][4 + (idx & 127)] = elem[l0 * 128 + idx];
  }
  for (int k = 0; k < 8; k++) {
    int idx = t + k * 256;
    feat_s[idx >> 8][132 + (idx & 255)] = chars[l0 * 256 + idx];
  }
  __syncthreads();
  const int c = t & 127, rh = t >> 7;
  float acc[4] = {0.f, 0.f, 0.f, 0.f};
  for (int f = 0; f < F1D; f++) {
    float w = W_in[f * CA + c];
#pragma unroll
    for (int r = 0; r < 4; r++) acc[r] += feat_s[rh * 4 + r][f] * w;
  }
#pragma unroll
  for (int r = 0; r < 4; r++) {
    int l = l0 + rh * 4 + r;
    out_cl[l * CA + c] = acc[r];
    out_q[l * CA + c] = acc[r];
    rcl_s[rh * 4 + r][c] = fmaxf(acc[r], 0.f);
  }
  __syncthreads();
  const int r = t >> 5, j = t & 15, mat = (t >> 4) & 1;
  const float* W = mat ? W_sm : W_sl;
  float a = 0.f;
  for (int i = 0; i < CA; i++) a += rcl_s[r][i] * W[i * CP + j];
  float* dst = mat ? csm : csl;
  dst[(l0 + r) * CP + j] = a;
}

// ---------------------------------------------------------------------------
// P[l][m][16] = Vf*(D@W_d + invd*W_invd + W_vm) + csl[l] + csm[m] ; + pair MLP
// also writes bias fp16 planes [b][h][l][m] = P @ Wb[b][:, h]
// block: 4 l x 128 m, 2 pairs/thread.
#define PM 128
__global__ __launch_bounds__(256) void k_pair(
    const float* __restrict__ pos, const int* __restrict__ uid,
    const float* __restrict__ csl, const float* __restrict__ csm,
    const float* __restrict__ W_d, const float* __restrict__ W_invd,
    const float* __restrict__ W_vm, const float* __restrict__ Wp1,
    const float* __restrict__ Wp2, const float* __restrict__ Wp3,
    const float* __restrict__ Wb,
    float* __restrict__ P_out, _Float16* __restrict__ bias_hp, int use_bias) {
  __shared__ float wp1_s[256], wp2_s[256], wp3_s[256];
  __shared__ float wd_s[48], winv_s[16], wvm_s[16], wb_s[192];
  __shared__ float csm_s[PM][17];
  __shared__ float posm_s[PM][3];
  __shared__ int uidm_s[PM];
  __shared__ float csl_s[4][16], posl_s[4][3];
  __shared__ int uidl_s[4];
  const int t = threadIdx.x;
  const int m0 = blockIdx.x * PM;
  const int l0 = blockIdx.y * 4;
  wp1_s[t] = Wp1[t];
  wp2_s[t] = Wp2[t];
  wp3_s[t] = Wp3[t];
  if (t < 48) wd_s[t] = W_d[t];
  if (t < 16) { winv_s[t] = W_invd[t]; wvm_s[t] = W_vm[t]; }
  if (t < 192) wb_s[t] = Wb[t];
  if (t < 64) csl_s[t >> 4][t & 15] = csl[l0 * 16 + t];
  if (t < 12) posl_s[t / 3][t % 3] = pos[l0 * 3 + t];
  if (t < 4) uidl_s[t] = uid[l0 + t];
  for (int k = 0; k < 8; k++) {
    int idx = t + k * 256;
    csm_s[idx >> 4][idx & 15] = csm[m0 * 16 + idx];
  }
  if (t < 128) uidm_s[t] = uid[m0 + t];
  if (t < 384) posm_s[t / 3][t % 3] = pos[m0 * 3 + t];
  {
    int idx = t + 256;
    if (idx < 384) posm_s[idx / 3][idx % 3] = pos[m0 * 3 + idx];
  }
  __syncthreads();
  const int li = t >> 6, mb = t & 63;
  const int l = l0 + li;
  float p[2][16], A[2][16], B[2][16];
#pragma unroll
  for (int pp = 0; pp < 2; pp++) {
    int mi = mb + pp * 64;
    float dx = posl_s[li][0] - posm_s[mi][0];
    float dy = posl_s[li][1] - posm_s[mi][1];
    float dz = posl_s[li][2] - posm_s[mi][2];
    bool vf = (uidl_s[li] == uidm_s[mi]);
    float invd = 1.f / (1.f + sqrtf(dx * dx + dy * dy + dz * dz));
#pragma unroll
    for (int c2 = 0; c2 < 16; c2++) {
      float base = dx * wd_s[c2] + dy * wd_s[16 + c2] + dz * wd_s[32 + c2] +
                   invd * winv_s[c2] + wvm_s[c2];
      p[pp][c2] = (vf ? base : 0.f) + csl_s[li][c2] + csm_s[mi][c2];
    }
  }
#pragma unroll
  for (int i = 0; i < 16; i++) {
    A[0][i] = fmaxf(p[0][i], 0.f);
    A[1][i] = fmaxf(p[1][i], 0.f);
  }
#pragma unroll
  for (int j = 0; j < 16; j++) {  // B = relu(A @ Wp1)
    float a0 = 0.f, a1 = 0.f;
#pragma unroll
    for (int i = 0; i < 16; i++) {
      float w = wp1_s[i * 16 + j];
      a0 += A[0][i] * w;
      a1 += A[1][i] * w;
    }
    B[0][j] = fmaxf(a0, 0.f);
    B[1][j] = fmaxf(a1, 0.f);
  }
#pragma unroll
  for (int j = 0; j < 16; j++) {  // A = relu(B @ Wp2)
    float a0 = 0.f, a1 = 0.f;
#pragma unroll
    for (int i = 0; i < 16; i++) {
      float w = wp2_s[i * 16 + j];
      a0 += B[0][i] * w;
      a1 += B[1][i] * w;
    }
    A[0][j] = fmaxf(a0, 0.f);
    A[1][j] = fmaxf(a1, 0.f);
  }
#pragma unroll
  for (int j = 0; j < 16; j++) {  // p += A @ Wp3
    float a0 = 0.f, a1 = 0.f;
#pragma unroll
    for (int i = 0; i < 16; i++) {
      float w = wp3_s[i * 16 + j];
      a0 += A[0][i] * w;
      a1 += A[1][i] * w;
    }
    p[0][j] += a0;
    p[1][j] += a1;
  }
#pragma unroll
  for (int pp = 0; pp < 2; pp++) {
    int m = m0 + mb + pp * 64;
    float* dst = P_out + ((size_t)l * L_ATOMS + m) * 16;
#pragma unroll
    for (int k = 0; k < 4; k++) {
      float4 v4 = make_float4(p[pp][4 * k], p[pp][4 * k + 1], p[pp][4 * k + 2],
                              p[pp][4 * k + 3]);
      *(float4*)(dst + 4 * k) = v4;
    }
    if (use_bias) {
#pragma unroll
      for (int bh = 0; bh < 12; bh++) {
        int bb = bh >> 2, h = bh & 3;
        float acc = 0.f;
#pragma unroll
        for (int c2 = 0; c2 < 16; c2++)
          acc += p[pp][c2] * wb_s[(bb * 16 + c2) * 4 + h];
        bias_hp[((size_t)(bb * 4 + h) * L_ATOMS + l) * L_ATOMS + m] =
            (_Float16)acc;
      }
    }
  }
}

// ---------------------------------------------------------------------------
// x = LN(Q); q/k (head-major fp16), v transposed vT[h][d][l] fp16. 8 rows/block.
__global__ __launch_bounds__(256) void k_lnqkv(
    const float* __restrict__ Qg, const float* __restrict__ Wq,
    const float* __restrict__ Wk, const float* __restrict__ Wv,
    _Float16* __restrict__ q_hd, _Float16* __restrict__ k_hd,
    _Float16* __restrict__ vT_hd) {
  __shared__ float x_s[8][CA];
  const int t = threadIdx.x;
  const int l0 = blockIdx.x * 8;
  ((float4*)x_s)[t] = ((const float4*)(Qg + l0 * CA))[t];
  __syncthreads();
  {
    const int r = t >> 5, i = t & 31;
    float s1 = 0.f, s2 = 0.f;
#pragma unroll
    for (int k = 0; k < 4; k++) {
      float x = x_s[r][i + 32 * k];
      s1 += x;
      s2 += x * x;
    }
#pragma unroll
    for (int m = 1; m <= 16; m <<= 1) {
      s1 += __shfl_xor(s1, m);
      s2 += __shfl_xor(s2, m);
    }
    float mu = s1 * (1.f / 128.f);
    float var = s2 * (1.f / 128.f) - mu * mu;
    float inv = 1.f / sqrtf(var + 1e-5f);
#pragma unroll
    for (int k = 0; k < 4; k++)
      x_s[r][i + 32 * k] = (x_s[r][i + 32 * k] - mu) * inv;
  }
  __syncthreads();
  const int c = t & 127, rh = t >> 7;
  const int h = c >> 5, d = c & 31;
#pragma unroll
  for (int mat = 0; mat < 3; mat++) {
    const float* W = mat == 0 ? Wq : (mat == 1 ? Wk : Wv);
    float acc[4] = {0.f, 0.f, 0.f, 0.f};
    for (int ii = 0; ii < CA; ii++) {
      float w = W[ii * CA + c];
#pragma unroll
      for (int rr = 0; rr < 4; rr++) acc[rr] += x_s[rh * 4 + rr][ii] * w;
    }
#pragma unroll
    for (int rr = 0; rr < 4; rr++) {
      int l = l0 + rh * 4 + rr;
      if (mat == 0)
        q_hd[(h * L_ATOMS + l) * HDIM + d] = (_Float16)acc[rr];
      else if (mat == 1)
        k_hd[(h * L_ATOMS + l) * HDIM + d] = (_Float16)acc[rr];
      else
        vT_hd[(h * HDIM + d) * L_ATOMS + l] = (_Float16)acc[rr];
    }
  }
}

// ---------------------------------------------------------------------------
// flash attention, one (16-row l-tile, head) per block; 4 waves split m-range.
template <int USE_BIAS>
__global__ __launch_bounds__(256) void k_attn(
    const _Float16* __restrict__ q_hd, const _Float16* __restrict__ k_hd,
    const _Float16* __restrict__ vT_hd, const _Float16* __restrict__ bias_hp,
    const float* __restrict__ Pmat, const float* __restrict__ Wb,
    float* __restrict__ o_buf, int b) {
  __shared__ __align__(16) _Float16 p_lds[4][16][40];
  __shared__ float o_sh[4][16][33];
  __shared__ float M_sh[4][16];
  __shared__ float S_sh[4][16];
  __shared__ float wb_s[16];
  const int t = threadIdx.x;
  const int w = t >> 6, lane = t & 63;
  const int l0 = blockIdx.x * 16;
  const int h = blockIdx.y;
  if (USE_BIAS == 0 && t < 16) wb_s[t] = Wb[(b * 16 + t) * 4 + h];
  __syncthreads();
  const int c16 = lane & 15, q4 = lane >> 4;
  half8 qa = *(const half8*)(q_hd + ((h * L_ATOMS + l0 + c16) * HDIM + q4 * 8));
  f32x4 o0 = {0.f, 0.f, 0.f, 0.f}, o1 = {0.f, 0.f, 0.f, 0.f};
  float M[4] = {-INFINITY, -INFINITY, -INFINITY, -INFINITY};
  float S[4] = {0.f, 0.f, 0.f, 0.f};
  const float scale = 0.17677669529663687f;  // 1/sqrt(32)
  for (int it = 0; it < 16; it++) {
    const int m0 = w * 512 + it * 32;
    half8 kb0 =
        *(const half8*)(k_hd + ((h * L_ATOMS + m0 + c16) * HDIM + q4 * 8));
    half8 kb1 =
        *(const half8*)(k_hd + ((h * L_ATOMS + m0 + 16 + c16) * HDIM + q4 * 8));
    f32x4 z = {0.f, 0.f, 0.f, 0.f};
    f32x4 c0 = __builtin_amdgcn_mfma_f32_16x16x32_f16(qa, kb0, z, 0, 0, 0);
    f32x4 c1 = __builtin_amdgcn_mfma_f32_16x16x32_f16(qa, kb1, z, 0, 0, 0);
    float l0v[4], l1v[4];
#pragma unroll
    for (int r = 0; r < 4; r++) {
      float b0, b1;
      if (USE_BIAS) {
        const _Float16* bp =
            bias_hp + ((size_t)(b * 4 + h) * L_ATOMS + (l0 + q4 * 4 + r)) *
                          L_ATOMS +
            m0 + c16;
        b0 = (float)bp[0];
        b1 = (float)bp[16];
      } else {
        const float* Pp0 =
            Pmat + ((size_t)(l0 + q4 * 4 + r) * L_ATOMS + m0 + c16) * 16;
        const float* Pp1 = Pp0 + 16 * 16;
        float a0 = 0.f, a1 = 0.f;
#pragma unroll
        for (int c2 = 0; c2 < 16; c2++) {
          a0 += Pp0[c2] * wb_s[c2];
          a1 += Pp1[c2] * wb_s[c2];
        }
        b0 = a0;
        b1 = a1;
      }
      l0v[r] = c0[r] * scale + b0;
      l1v[r] = c1[r] * scale + b1;
    }
#pragma unroll
    for (int r = 0; r < 4; r++) {
      float tm = grp16_max(fmaxf(l0v[r], l1v[r]));
      float Mn = fmaxf(M[r], tm);
      float al = __expf(M[r] - Mn);
      float p0 = __expf(l0v[r] - Mn);
      float p1 = __expf(l1v[r] - Mn);
      float rs = grp16_sum(p0 + p1);
      S[r] = S[r] * al + rs;
      M[r] = Mn;
      o0[r] *= al;
      o1[r] *= al;
      p_lds[w][q4 * 4 + r][c16] = (_Float16)p0;
      p_lds[w][q4 * 4 + r][16 + c16] = (_Float16)p1;
    }
    __syncthreads();
    half8 pa = *(const half8*)(&p_lds[w][c16][q4 * 8]);
    half8 vb0 =
        *(const half8*)(vT_hd + ((h * HDIM + c16) * L_ATOMS + m0 + q4 * 8));
    half8 vb1 = *(const half8*)(vT_hd +
                                ((h * HDIM + 16 + c16) * L_ATOMS + m0 + q4 * 8));
    o0 = __builtin_amdgcn_mfma_f32_16x16x32_f16(pa, vb0, o0, 0, 0, 0);
    o1 = __builtin_amdgcn_mfma_f32_16x16x32_f16(pa, vb1, o1, 0, 0, 0);
    __syncthreads();
  }
#pragma unroll
  for (int r = 0; r < 4; r++) {
    o_sh[w][q4 * 4 + r][c16] = o0[r];
    o_sh[w][q4 * 4 + r][16 + c16] = o1[r];
  }
  if (c16 == 0) {
#pragma unroll
    for (int r = 0; r < 4; r++) {
      M_sh[w][q4 * 4 + r] = M[r];
      S_sh[w][q4 * 4 + r] = S[r];
    }
  }
  __syncthreads();
  {
    const int d = t & 31, r8 = t >> 5;
#pragma unroll
    for (int k = 0; k < 2; k++) {
      int row = r8 + 8 * k;
      float Mg = fmaxf(fmaxf(M_sh[0][row], M_sh[1][row]),
                       fmaxf(M_sh[2][row], M_sh[3][row]));
      float Sg = 0.f, ov = 0.f;
#pragma unroll
      for (int ww = 0; ww < 4; ww++) {
        float e = __expf(M_sh[ww][row] - Mg);
        Sg += S_sh[ww][row] * e;
        ov += o_sh[ww][row][d] * e;
      }
      o_buf[(l0 + row) * CA + h * HDIM + d] = ov / Sg;
    }
  }
}

// ---------------------------------------------------------------------------
// Q += o@Wo ; y = LN(Q) ; Q += relu(y@Wt1)@Wt2.  8 rows/block.
__global__ __launch_bounds__(256) void k_ffn(
    float* __restrict__ Qg, const float* __restrict__ o_buf,
    const float* __restrict__ Wo, const float* __restrict__ Wt1,
    const float* __restrict__ Wt2) {
  __shared__ float o_s[8][CA];
  __shared__ float q_s[8][CA];
  __shared__ float h_s[8][FFD];
  const int t = threadIdx.x;
  const int l0 = blockIdx.x * 8;
  ((float4*)o_s)[t] = ((const float4*)(o_buf + l0 * CA))[t];
  ((float4*)q_s)[t] = ((const float4*)(Qg + l0 * CA))[t];
  __syncthreads();
  const int c = t & 127, rh = t >> 7;
  {
    float acc[4] = {0.f, 0.f, 0.f, 0.f};
    for (int i = 0; i < CA; i++) {
      float wv = Wo[i * CA + c];
#pragma unroll
      for (int r = 0; r < 4; r++) acc[r] += o_s[rh * 4 + r][i] * wv;
    }
#pragma unroll
    for (int r = 0; r < 4; r++) q_s[rh * 4 + r][c] += acc[r];
  }
  __syncthreads();
  {
    const int r = t >> 5, i = t & 31;
    float s1 = 0.f, s2 = 0.f;
#pragma unroll
    for (int k = 0; k < 4; k++) {
      float x = q_s[r][i + 32 * k];
      s1 += x;
      s2 += x * x;
    }
#pragma unroll
    for (int m = 1; m <= 16; m <<= 1) {
      s1 += __shfl_xor(s1, m);
      s2 += __shfl_xor(s2, m);
    }
    float mu = s1 * (1.f / 128.f);
    float var = s2 * (1.f / 128.f) - mu * mu;
    float inv = 1.f / sqrtf(var + 1e-5f);
#pragma unroll
    for (int k = 0; k < 4; k++)
      o_s[r][i + 32 * k] = (q_s[r][i + 32 * k] - mu) * inv;
  }
  __syncthreads();
  {
    float a1[8], a2[8];
#pragma unroll
    for (int r = 0; r < 8; r++) {
      a1[r] = 0.f;
      a2[r] = 0.f;
    }
    for (int i = 0; i < CA; i++) {
      float w1 = Wt1[i * FFD + t];
      float w2 = Wt1[i * FFD + 256 + t];
#pragma unroll
      for (int r = 0; r < 8; r++) {
        float y = o_s[r][i];
        a1[r] += y * w1;
        a2[r] += y * w2;
      }
    }
#pragma unroll
    for (int r = 0; r < 8; r++) {
      h_s[r][t] = fmaxf(a1[r], 0.f);
      h_s[r][256 + t] = fmaxf(a2[r], 0.f);
    }
  }
  __syncthreads();
  {
    float acc[4] = {0.f, 0.f, 0.f, 0.f};
    for (int j = 0; j < FFD; j++) {
      float wv = Wt2[j * CA + c];
#pragma unroll
      for (int r = 0; r < 4; r++) acc[r] += h_s[rh * 4 + r][j] * wv;
    }
#pragma unroll
    for (int r = 0; r < 4; r++) {
      int l = l0 + rh * 4 + r;
      Qg[l * CA + c] = q_s[rh * 4 + r][c] + acc[r];
    }
  }
}

// ---------------------------------------------------------------------------
// A_I[i] = mean over atoms of relu(Q@Wq_tok); one block per token, sorted map.
__global__ __launch_bounds__(384) void k_token(
    const float* __restrict__ Qg, const float* __restrict__ Wq_tok,
    const int* __restrict__ tok, float* __restrict__ A_I) {
  __shared__ float q_s[16][CA];
  __shared__ int lo_s, hi_s;
  const int i = blockIdx.x;
  const int t = threadIdx.x;
  if (t == 0) {
    int lo = 0, hi = L_ATOMS;
    while (lo < hi) {
      int mid = (lo + hi) >> 1;
      if (tok[mid] < i) lo = mid + 1; else hi = mid;
    }
    lo_s = lo;
    int lo2 = lo, hi2 = L_ATOMS;
    while (lo2 < hi2) {
      int mid = (lo2 + hi2) >> 1;
      if (tok[mid] < i + 1) lo2 = mid + 1; else hi2 = mid;
    }
    hi_s = lo2;
  }
  __syncthreads();
  const int lo = lo_s, hi = hi_s;
  float acc = 0.f;
  for (int a0 = lo; a0 < hi; a0 += 16) {
    int n = min(16, hi - a0);
    for (int idx = t; idx < n * CA; idx += 384)
      q_s[idx >> 7][idx & 127] = Qg[a0 * CA + idx];
    __syncthreads();
    float s[16];
#pragma unroll
    for (int jj = 0; jj < 16; jj++) s[jj] = 0.f;
    for (int k = 0; k < CA; k++) {
      float wv = Wq_tok[k * CT + t];
#pragma unroll
      for (int jj = 0; jj < 16; jj++) s[jj] += q_s[jj][k] * wv;
    }
    for (int jj = 0; jj < n; jj++) acc += fmaxf(s[jj], 0.f);
    __syncthreads();
  }
  int cnt = hi - lo;
  A_I[i * CT + t] = cnt > 0 ? acc / (float)cnt : 0.f;
}

// ---------------------------------------------------------------------------
extern "C" void kernel_launch(void* const* d_in, const int* in_sizes, int n_in,
                              void* d_out, int out_size, void* d_ws,
                              size_t ws_size, hipStream_t stream) {
  const float* pos = (const float*)d_in[0];
  const float* charge = (const float*)d_in[1];
  const float* elem = (const float*)d_in[2];
  const float* chars = (const float*)d_in[3];
  const int* uid = (const int*)d_in[4];
  const int* tok = (const int*)d_in[5];
  const float* W_in = (const float*)d_in[6];
  const float* W_d = (const float*)d_in[7];
  const float* W_invd = (const float*)d_in[8];
  const float* W_vm = (const float*)d_in[9];
  const float* W_sl = (const float*)d_in[10];
  const float* W_sm = (const float*)d_in[11];
  const float* Wp1 = (const float*)d_in[12];
  const float* Wp2 = (const float*)d_in[13];
  const float* Wp3 = (const float*)d_in[14];
  const float* Wq_tok = (const float*)d_in[15];
  const float* Wq = (const float*)d_in[16];
  const float* Wk = (const float*)d_in[17];
  const float* Wv = (const float*)d_in[18];
  const float* Wb = (const float*)d_in[19];
  const float* Wo = (const float*)d_in[20];
  const float* Wt1 = (const float*)d_in[21];
  const float* Wt2 = (const float*)d_in[22];

  float* out = (float*)d_out;
  float* A_I = out;                   // 512*384
  float* Qg = out + 196608;           // 2048*128 (working residual stream)
  float* C_Lo = out + 458752;         // 2048*128
  float* P_out = out + 720896;        // 2048*2048*16

  char* ws = (char*)d_ws;
  float* csl = (float*)(ws + 0);                        // 128 KB
  float* csm = (float*)(ws + 131072);                   // 128 KB
  _Float16* q_hd = (_Float16*)(ws + 262144);            // 512 KB
  _Float16* k_hd = (_Float16*)(ws + 262144 + 524288);   // 512 KB
  _Float16* vT_hd = (_Float16*)(ws + 262144 + 2 * 524288);  // 512 KB
  float* o_buf = (float*)(ws + 262144 + 3 * 524288);    // 1 MB
  _Float16* bias_hp = (_Float16*)(ws + 262144 + 3 * 524288 + 1048576);
  size_t need =
      262144 + 3 * 524288 + 1048576 + (size_t)NBLK * NHEAD * L_ATOMS * L_ATOMS * 2;
  int use_bias = (ws_size >= need) ? 1 : 0;

  k_cl<<<256, 256, 0, stream>>>(pos, charge, elem, chars, W_in, W_sl, W_sm,
                                C_Lo, Qg, csl, csm);
  k_pair<<<dim3(16, 512), 256, 0, stream>>>(pos, uid, csl, csm, W_d, W_invd,
                                            W_vm, Wp1, Wp2, Wp3, Wb, P_out,
                                            bias_hp, use_bias);
  for (int b = 0; b < NBLK; b++) {
    k_lnqkv<<<256, 256, 0, stream>>>(Qg, Wq + b * 16384, Wk + b * 16384,
                                     Wv + b * 16384, q_hd, k_hd, vT_hd);
    if (use_bias)
      k_attn<1><<<dim3(128, 4), 256, 0, stream>>>(q_hd, k_hd, vT_hd, bias_hp,
                                                  P_out, Wb, o_buf, b);
    else
      k_attn<0><<<dim3(128, 4), 256, 0, stream>>>(q_hd, k_hd, vT_hd, bias_hp,
                                                  P_out, Wb, o_buf, b);
    k_ffn<<<256, 256, 0, stream>>>(Qg, o_buf, Wo + b * 16384, Wt1 + b * 65536,
                                   Wt2 + b * 65536);
  }
  k_token<<<512, 384, 0, stream>>>(Qg, Wq_tok, tok, A_I);
}

// Round 2
// 878.235 us; speedup vs baseline: 2.5469x; 2.5469x over previous
//
#include <hip/hip_runtime.h>
#include <hip/hip_bf16.h>
#include <hip/hip_fp16.h>

#define L_ATOMS 2048
#define N_TOK 512
#define CA 128
#define CP 16
#define CT 384
#define NBLK 3
#define NHEAD 4
#define HDIM 32
#define FFD 512
#define F1D 388

typedef _Float16 half8 __attribute__((ext_vector_type(8)));
typedef float f32x4 __attribute__((ext_vector_type(4)));

__device__ __forceinline__ float grp16_max(float v) {
  v = fmaxf(v, __shfl_xor(v, 1));
  v = fmaxf(v, __shfl_xor(v, 2));
  v = fmaxf(v, __shfl_xor(v, 4));
  v = fmaxf(v, __shfl_xor(v, 8));
  return v;
}
__device__ __forceinline__ float grp16_sum(float v) {
  v += __shfl_xor(v, 1);
  v += __shfl_xor(v, 2);
  v += __shfl_xor(v, 4);
  v += __shfl_xor(v, 8);
  return v;
}

// ---------------------------------------------------------------------------
// C_L = feat @ W_in ; Q init = C_L ; csl = relu(C_L)@W_sl ; csm = relu(C_L)@W_sm
// 8 atoms per block, 256 threads.
__global__ __launch_bounds__(256) void k_cl(
    const float* __restrict__ pos, const float* __restrict__ charge,
    const float* __restrict__ elem, const float* __restrict__ chars,
    const float* __restrict__ W_in, const float* __restrict__ W_sl,
    const float* __restrict__ W_sm,
    float* __restrict__ out_cl, float* __restrict__ out_q,
    float* __restrict__ csl, float* __restrict__ csm) {
  __shared__ float feat_s[8][F1D];
  __shared__ float rcl_s[8][CA];
  const int t = threadIdx.x;
  const int l0 = blockIdx.x * 8;
  if (t < 24) feat_s[t / 3][t % 3] = pos[l0 * 3 + t];
  else if (t < 32) feat_s[t - 24][3] = charge[l0 + t - 24];
  for (int k = 0; k < 4; k++) {
    int idx = t + k * 256;
    feat_s[idx >> 7][4 + (idx & 127)] = elem[l0 * 128 + idx];
  }
  for (int k = 0; k < 8; k++) {
    int idx = t + k * 256;
    feat_s[idx >> 8][132 + (idx & 255)] = chars[l0 * 256 + idx];
  }
  __syncthreads();
  const int c = t & 127, rh = t >> 7;
  float acc[4] = {0.f, 0.f, 0.f, 0.f};
  for (int f = 0; f < F1D; f++) {
    float w = W_in[f * CA + c];
#pragma unroll
    for (int r = 0; r < 4; r++) acc[r] += feat_s[rh * 4 + r][f] * w;
  }
#pragma unroll
  for (int r = 0; r < 4; r++) {
    int l = l0 + rh * 4 + r;
    out_cl[l * CA + c] = acc[r];
    out_q[l * CA + c] = acc[r];
    rcl_s[rh * 4 + r][c] = fmaxf(acc[r], 0.f);
  }
  __syncthreads();
  const int r = t >> 5, j = t & 15, mat = (t >> 4) & 1;
  const float* W = mat ? W_sm : W_sl;
  float a = 0.f;
  for (int i = 0; i < CA; i++) a += rcl_s[r][i] * W[i * CP + j];
  float* dst = mat ? csm : csl;
  dst[(l0 + r) * CP + j] = a;
}

// ---------------------------------------------------------------------------
// P[l][m][16] = Vf*(D@W_d + invd*W_invd + W_vm) + csl[l] + csm[m] ; + pair MLP
// also writes bias fp16 planes [b][h][l][m] = P @ Wb[b][:, h]
// ONE pair per thread (register-pressure fix); block = 2 l-rows x 128 m.
__global__ __launch_bounds__(256, 4) void k_pair(
    const float* __restrict__ pos, const int* __restrict__ uid,
    const float* __restrict__ csl, const float* __restrict__ csm,
    const float* __restrict__ W_d, const float* __restrict__ W_invd,
    const float* __restrict__ W_vm, const float* __restrict__ Wp1,
    const float* __restrict__ Wp2, const float* __restrict__ Wp3,
    const float* __restrict__ Wb,
    float* __restrict__ P_out, _Float16* __restrict__ bias_hp, int use_bias) {
  __shared__ __align__(16) float wp1_s[256], wp2_s[256], wp3_s[256];
  __shared__ float wd_s[48], winv_s[16], wvm_s[16];
  __shared__ __align__(16) float wbT_s[16][12];  // [c2][b*4+h], rows 48B
  __shared__ float csm_s[128][17];
  __shared__ float posm_s[128][4];
  __shared__ int uidm_s[128];
  __shared__ float csl_s[2][16];
  __shared__ float posl_s[2][4];
  __shared__ int uidl_s[2];
  const int t = threadIdx.x;
  const int m0 = blockIdx.x * 128;
  const int l0 = blockIdx.y * 2;
  wp1_s[t] = Wp1[t];
  wp2_s[t] = Wp2[t];
  wp3_s[t] = Wp3[t];
  if (t < 48) wd_s[t] = W_d[t];
  if (t < 16) { winv_s[t] = W_invd[t]; wvm_s[t] = W_vm[t]; }
  if (t < 192) {  // Wb flat (bb*16+c2)*4+h == t
    int bb = t >> 6, c2 = (t >> 2) & 15, h = t & 3;
    wbT_s[c2][bb * 4 + h] = Wb[t];
  }
  if (t < 32) csl_s[t >> 4][t & 15] = csl[l0 * 16 + t];
  if (t < 6) posl_s[t / 3][t % 3] = pos[l0 * 3 + t];
  if (t < 2) uidl_s[t] = uid[l0 + t];
  for (int k = 0; k < 8; k++) {
    int idx = t + k * 256;
    csm_s[idx >> 4][idx & 15] = csm[m0 * 16 + idx];
  }
  if (t < 128) uidm_s[t] = uid[m0 + t];
  if (t < 384) posm_s[t / 3][t % 3] = pos[m0 * 3 + t];
  {
    int idx = t + 256;
    if (idx < 384) posm_s[idx / 3][idx % 3] = pos[m0 * 3 + idx];
  }
  __syncthreads();
  const int li = t >> 7, mi = t & 127;
  float dx = posl_s[li][0] - posm_s[mi][0];
  float dy = posl_s[li][1] - posm_s[mi][1];
  float dz = posl_s[li][2] - posm_s[mi][2];
  float vfm = (uidl_s[li] == uidm_s[mi]) ? 1.f : 0.f;
  float invd_v = vfm / (1.f + sqrtf(dx * dx + dy * dy + dz * dz));
  float dxv = dx * vfm, dyv = dy * vfm, dzv = dz * vfm;
  float pv[16], A[16], B[16];
#pragma unroll
  for (int c = 0; c < 16; c++) {
    pv[c] = dxv * wd_s[c] + dyv * wd_s[16 + c] + dzv * wd_s[32 + c] +
            invd_v * winv_s[c] + vfm * wvm_s[c] + csl_s[li][c] + csm_s[mi][c];
    A[c] = fmaxf(pv[c], 0.f);
  }
  // layer1: B = relu(A @ Wp1)
#pragma unroll
  for (int jg = 0; jg < 4; jg++) {
    float ax = 0.f, ay = 0.f, az = 0.f, aw = 0.f;
#pragma unroll
    for (int i = 0; i < 16; i++) {
      float4 w = *(const float4*)&wp1_s[i * 16 + jg * 4];
      float ai = A[i];
      ax += ai * w.x; ay += ai * w.y; az += ai * w.z; aw += ai * w.w;
    }
    B[jg * 4 + 0] = fmaxf(ax, 0.f);
    B[jg * 4 + 1] = fmaxf(ay, 0.f);
    B[jg * 4 + 2] = fmaxf(az, 0.f);
    B[jg * 4 + 3] = fmaxf(aw, 0.f);
  }
  // layer2: A = relu(B @ Wp2)
#pragma unroll
  for (int jg = 0; jg < 4; jg++) {
    float ax = 0.f, ay = 0.f, az = 0.f, aw = 0.f;
#pragma unroll
    for (int i = 0; i < 16; i++) {
      float4 w = *(const float4*)&wp2_s[i * 16 + jg * 4];
      float bi = B[i];
      ax += bi * w.x; ay += bi * w.y; az += bi * w.z; aw += bi * w.w;
    }
    A[jg * 4 + 0] = fmaxf(ax, 0.f);
    A[jg * 4 + 1] = fmaxf(ay, 0.f);
    A[jg * 4 + 2] = fmaxf(az, 0.f);
    A[jg * 4 + 3] = fmaxf(aw, 0.f);
  }
  // layer3: pv += A @ Wp3
#pragma unroll
  for (int jg = 0; jg < 4; jg++) {
    float ax = 0.f, ay = 0.f, az = 0.f, aw = 0.f;
#pragma unroll
    for (int i = 0; i < 16; i++) {
      float4 w = *(const float4*)&wp3_s[i * 16 + jg * 4];
      float ai = A[i];
      ax += ai * w.x; ay += ai * w.y; az += ai * w.z; aw += ai * w.w;
    }
    pv[jg * 4 + 0] += ax;
    pv[jg * 4 + 1] += ay;
    pv[jg * 4 + 2] += az;
    pv[jg * 4 + 3] += aw;
  }
  {
    float* dst = P_out + ((size_t)(l0 + li) * L_ATOMS + (m0 + mi)) * 16;
#pragma unroll
    for (int k2 = 0; k2 < 4; k2++)
      *(float4*)(dst + 4 * k2) = make_float4(pv[4 * k2], pv[4 * k2 + 1],
                                             pv[4 * k2 + 2], pv[4 * k2 + 3]);
  }
  if (use_bias) {
    _Float16* bp =
        bias_hp + (size_t)(l0 + li) * L_ATOMS + (m0 + mi);
    const size_t plane = (size_t)L_ATOMS * L_ATOMS;
#pragma unroll
    for (int g = 0; g < 3; g++) {
      float ax = 0.f, ay = 0.f, az = 0.f, aw = 0.f;
#pragma unroll
      for (int c = 0; c < 16; c++) {
        float4 w = *(const float4*)&wbT_s[c][g * 4];
        float pc = pv[c];
        ax += pc * w.x; ay += pc * w.y; az += pc * w.z; aw += pc * w.w;
      }
      _Float16* b0 = bp + (size_t)(g * 4) * plane;
      b0[0] = (_Float16)ax;
      b0[plane] = (_Float16)ay;
      b0[2 * plane] = (_Float16)az;
      b0[3 * plane] = (_Float16)aw;
    }
  }
}

// ---------------------------------------------------------------------------
// x = LN(Q); q/k (head-major fp16), v transposed vT[h][d][l] fp16. 8 rows/block.
__global__ __launch_bounds__(256) void k_lnqkv(
    const float* __restrict__ Qg, const float* __restrict__ Wq,
    const float* __restrict__ Wk, const float* __restrict__ Wv,
    _Float16* __restrict__ q_hd, _Float16* __restrict__ k_hd,
    _Float16* __restrict__ vT_hd) {
  __shared__ float x_s[8][CA];
  const int t = threadIdx.x;
  const int l0 = blockIdx.x * 8;
  ((float4*)x_s)[t] = ((const float4*)(Qg + l0 * CA))[t];
  __syncthreads();
  {
    const int r = t >> 5, i = t & 31;
    float s1 = 0.f, s2 = 0.f;
#pragma unroll
    for (int k = 0; k < 4; k++) {
      float x = x_s[r][i + 32 * k];
      s1 += x;
      s2 += x * x;
    }
#pragma unroll
    for (int m = 1; m <= 16; m <<= 1) {
      s1 += __shfl_xor(s1, m);
      s2 += __shfl_xor(s2, m);
    }
    float mu = s1 * (1.f / 128.f);
    float var = s2 * (1.f / 128.f) - mu * mu;
    float inv = 1.f / sqrtf(var + 1e-5f);
#pragma unroll
    for (int k = 0; k < 4; k++)
      x_s[r][i + 32 * k] = (x_s[r][i + 32 * k] - mu) * inv;
  }
  __syncthreads();
  const int c = t & 127, rh = t >> 7;
  const int h = c >> 5, d = c & 31;
#pragma unroll
  for (int mat = 0; mat < 3; mat++) {
    const float* W = mat == 0 ? Wq : (mat == 1 ? Wk : Wv);
    float acc[4] = {0.f, 0.f, 0.f, 0.f};
    for (int ii = 0; ii < CA; ii++) {
      float w = W[ii * CA + c];
#pragma unroll
      for (int rr = 0; rr < 4; rr++) acc[rr] += x_s[rh * 4 + rr][ii] * w;
    }
#pragma unroll
    for (int rr = 0; rr < 4; rr++) {
      int l = l0 + rh * 4 + rr;
      if (mat == 0)
        q_hd[(h * L_ATOMS + l) * HDIM + d] = (_Float16)acc[rr];
      else if (mat == 1)
        k_hd[(h * L_ATOMS + l) * HDIM + d] = (_Float16)acc[rr];
      else
        vT_hd[(h * HDIM + d) * L_ATOMS + l] = (_Float16)acc[rr];
    }
  }
}

// ---------------------------------------------------------------------------
// flash attention, one (16-row l-tile, head) per block; 4 waves split m-range.
template <int USE_BIAS>
__global__ __launch_bounds__(256) void k_attn(
    const _Float16* __restrict__ q_hd, const _Float16* __restrict__ k_hd,
    const _Float16* __restrict__ vT_hd, const _Float16* __restrict__ bias_hp,
    const float* __restrict__ Pmat, const float* __restrict__ Wb,
    float* __restrict__ o_buf, int b) {
  __shared__ __align__(16) _Float16 p_lds[4][16][40];
  __shared__ float o_sh[4][16][33];
  __shared__ float M_sh[4][16];
  __shared__ float S_sh[4][16];
  __shared__ float wb_s[16];
  const int t = threadIdx.x;
  const int w = t >> 6, lane = t & 63;
  const int l0 = blockIdx.x * 16;
  const int h = blockIdx.y;
  if (USE_BIAS == 0 && t < 16) wb_s[t] = Wb[(b * 16 + t) * 4 + h];
  __syncthreads();
  const int c16 = lane & 15, q4 = lane >> 4;
  half8 qa = *(const half8*)(q_hd + ((h * L_ATOMS + l0 + c16) * HDIM + q4 * 8));
  f32x4 o0 = {0.f, 0.f, 0.f, 0.f}, o1 = {0.f, 0.f, 0.f, 0.f};
  float M[4] = {-INFINITY, -INFINITY, -INFINITY, -INFINITY};
  float S[4] = {0.f, 0.f, 0.f, 0.f};
  const float scale = 0.17677669529663687f;  // 1/sqrt(32)
  for (int it = 0; it < 16; it++) {
    const int m0 = w * 512 + it * 32;
    half8 kb0 =
        *(const half8*)(k_hd + ((h * L_ATOMS + m0 + c16) * HDIM + q4 * 8));
    half8 kb1 =
        *(const half8*)(k_hd + ((h * L_ATOMS + m0 + 16 + c16) * HDIM + q4 * 8));
    f32x4 z = {0.f, 0.f, 0.f, 0.f};
    f32x4 c0 = __builtin_amdgcn_mfma_f32_16x16x32_f16(qa, kb0, z, 0, 0, 0);
    f32x4 c1 = __builtin_amdgcn_mfma_f32_16x16x32_f16(qa, kb1, z, 0, 0, 0);
    float l0v[4], l1v[4];
#pragma unroll
    for (int r = 0; r < 4; r++) {
      float b0, b1;
      if (USE_BIAS) {
        const _Float16* bp =
            bias_hp + ((size_t)(b * 4 + h) * L_ATOMS + (l0 + q4 * 4 + r)) *
                          L_ATOMS +
            m0 + c16;
        b0 = (float)bp[0];
        b1 = (float)bp[16];
      } else {
        const float* Pp0 =
            Pmat + ((size_t)(l0 + q4 * 4 + r) * L_ATOMS + m0 + c16) * 16;
        const float* Pp1 = Pp0 + 16 * 16;
        float a0 = 0.f, a1 = 0.f;
#pragma unroll
        for (int c2 = 0; c2 < 16; c2++) {
          a0 += Pp0[c2] * wb_s[c2];
          a1 += Pp1[c2] * wb_s[c2];
        }
        b0 = a0;
        b1 = a1;
      }
      l0v[r] = c0[r] * scale + b0;
      l1v[r] = c1[r] * scale + b1;
    }
#pragma unroll
    for (int r = 0; r < 4; r++) {
      float tm = grp16_max(fmaxf(l0v[r], l1v[r]));
      float Mn = fmaxf(M[r], tm);
      float al = __expf(M[r] - Mn);
      float p0 = __expf(l0v[r] - Mn);
      float p1 = __expf(l1v[r] - Mn);
      float rs = grp16_sum(p0 + p1);
      S[r] = S[r] * al + rs;
      M[r] = Mn;
      o0[r] *= al;
      o1[r] *= al;
      p_lds[w][q4 * 4 + r][c16] = (_Float16)p0;
      p_lds[w][q4 * 4 + r][16 + c16] = (_Float16)p1;
    }
    __syncthreads();
    half8 pa = *(const half8*)(&p_lds[w][c16][q4 * 8]);
    half8 vb0 =
        *(const half8*)(vT_hd + ((h * HDIM + c16) * L_ATOMS + m0 + q4 * 8));
    half8 vb1 = *(const half8*)(vT_hd +
                                ((h * HDIM + 16 + c16) * L_ATOMS + m0 + q4 * 8));
    o0 = __builtin_amdgcn_mfma_f32_16x16x32_f16(pa, vb0, o0, 0, 0, 0);
    o1 = __builtin_amdgcn_mfma_f32_16x16x32_f16(pa, vb1, o1, 0, 0, 0);
    __syncthreads();
  }
#pragma unroll
  for (int r = 0; r < 4; r++) {
    o_sh[w][q4 * 4 + r][c16] = o0[r];
    o_sh[w][q4 * 4 + r][16 + c16] = o1[r];
  }
  if (c16 == 0) {
#pragma unroll
    for (int r = 0; r < 4; r++) {
      M_sh[w][q4 * 4 + r] = M[r];
      S_sh[w][q4 * 4 + r] = S[r];
    }
  }
  __syncthreads();
  {
    const int d = t & 31, r8 = t >> 5;
#pragma unroll
    for (int k = 0; k < 2; k++) {
      int row = r8 + 8 * k;
      float Mg = fmaxf(fmaxf(M_sh[0][row], M_sh[1][row]),
                       fmaxf(M_sh[2][row], M_sh[3][row]));
      float Sg = 0.f, ov = 0.f;
#pragma unroll
      for (int ww = 0; ww < 4; ww++) {
        float e = __expf(M_sh[ww][row] - Mg);
        Sg += S_sh[ww][row] * e;
        ov += o_sh[ww][row][d] * e;
      }
      o_buf[(l0 + row) * CA + h * HDIM + d] = ov / Sg;
    }
  }
}

// ---------------------------------------------------------------------------
// Q += o@Wo ; y = LN(Q) ; Q += relu(y@Wt1)@Wt2.  8 rows/block.
__global__ __launch_bounds__(256) void k_ffn(
    float* __restrict__ Qg, const float* __restrict__ o_buf,
    const float* __restrict__ Wo, const float* __restrict__ Wt1,
    const float* __restrict__ Wt2) {
  __shared__ float o_s[8][CA];
  __shared__ float q_s[8][CA];
  __shared__ float h_s[8][FFD];
  const int t = threadIdx.x;
  const int l0 = blockIdx.x * 8;
  ((float4*)o_s)[t] = ((const float4*)(o_buf + l0 * CA))[t];
  ((float4*)q_s)[t] = ((const float4*)(Qg + l0 * CA))[t];
  __syncthreads();
  const int c = t & 127, rh = t >> 7;
  {
    float acc[4] = {0.f, 0.f, 0.f, 0.f};
    for (int i = 0; i < CA; i++) {
      float wv = Wo[i * CA + c];
#pragma unroll
      for (int r = 0; r < 4; r++) acc[r] += o_s[rh * 4 + r][i] * wv;
    }
#pragma unroll
    for (int r = 0; r < 4; r++) q_s[rh * 4 + r][c] += acc[r];
  }
  __syncthreads();
  {
    const int r = t >> 5, i = t & 31;
    float s1 = 0.f, s2 = 0.f;
#pragma unroll
    for (int k = 0; k < 4; k++) {
      float x = q_s[r][i + 32 * k];
      s1 += x;
      s2 += x * x;
    }
#pragma unroll
    for (int m = 1; m <= 16; m <<= 1) {
      s1 += __shfl_xor(s1, m);
      s2 += __shfl_xor(s2, m);
    }
    float mu = s1 * (1.f / 128.f);
    float var = s2 * (1.f / 128.f) - mu * mu;
    float inv = 1.f / sqrtf(var + 1e-5f);
#pragma unroll
    for (int k = 0; k < 4; k++)
      o_s[r][i + 32 * k] = (q_s[r][i + 32 * k] - mu) * inv;
  }
  __syncthreads();
  {
    float a1[8], a2[8];
#pragma unroll
    for (int r = 0; r < 8; r++) {
      a1[r] = 0.f;
      a2[r] = 0.f;
    }
    for (int i = 0; i < CA; i++) {
      float w1 = Wt1[i * FFD + t];
      float w2 = Wt1[i * FFD + 256 + t];
#pragma unroll
      for (int r = 0; r < 8; r++) {
        float y = o_s[r][i];
        a1[r] += y * w1;
        a2[r] += y * w2;
      }
    }
#pragma unroll
    for (int r = 0; r < 8; r++) {
      h_s[r][t] = fmaxf(a1[r], 0.f);
      h_s[r][256 + t] = fmaxf(a2[r], 0.f);
    }
  }
  __syncthreads();
  {
    float acc[4] = {0.f, 0.f, 0.f, 0.f};
    for (int j = 0; j < FFD; j++) {
      float wv = Wt2[j * CA + c];
#pragma unroll
      for (int r = 0; r < 4; r++) acc[r] += h_s[rh * 4 + r][j] * wv;
    }
#pragma unroll
    for (int r = 0; r < 4; r++) {
      int l = l0 + rh * 4 + r;
      Qg[l * CA + c] = q_s[rh * 4 + r][c] + acc[r];
    }
  }
}

// ---------------------------------------------------------------------------
// A_I[i] = mean over atoms of relu(Q@Wq_tok); one block per token, sorted map.
__global__ __launch_bounds__(384) void k_token(
    const float* __restrict__ Qg, const float* __restrict__ Wq_tok,
    const int* __restrict__ tok, float* __restrict__ A_I) {
  __shared__ float q_s[16][CA];
  __shared__ int lo_s, hi_s;
  const int i = blockIdx.x;
  const int t = threadIdx.x;
  if (t == 0) {
    int lo = 0, hi = L_ATOMS;
    while (lo < hi) {
      int mid = (lo + hi) >> 1;
      if (tok[mid] < i) lo = mid + 1; else hi = mid;
    }
    lo_s = lo;
    int lo2 = lo, hi2 = L_ATOMS;
    while (lo2 < hi2) {
      int mid = (lo2 + hi2) >> 1;
      if (tok[mid] < i + 1) lo2 = mid + 1; else hi2 = mid;
    }
    hi_s = lo2;
  }
  __syncthreads();
  const int lo = lo_s, hi = hi_s;
  float acc = 0.f;
  for (int a0 = lo; a0 < hi; a0 += 16) {
    int n = min(16, hi - a0);
    for (int idx = t; idx < n * CA; idx += 384)
      q_s[idx >> 7][idx & 127] = Qg[a0 * CA + idx];
    __syncthreads();
    float s[16];
#pragma unroll
    for (int jj = 0; jj < 16; jj++) s[jj] = 0.f;
    for (int k = 0; k < CA; k++) {
      float wv = Wq_tok[k * CT + t];
#pragma unroll
      for (int jj = 0; jj < 16; jj++) s[jj] += q_s[jj][k] * wv;
    }
    for (int jj = 0; jj < n; jj++) acc += fmaxf(s[jj], 0.f);
    __syncthreads();
  }
  int cnt = hi - lo;
  A_I[i * CT + t] = cnt > 0 ? acc / (float)cnt : 0.f;
}

// ---------------------------------------------------------------------------
extern "C" void kernel_launch(void* const* d_in, const int* in_sizes, int n_in,
                              void* d_out, int out_size, void* d_ws,
                              size_t ws_size, hipStream_t stream) {
  const float* pos = (const float*)d_in[0];
  const float* charge = (const float*)d_in[1];
  const float* elem = (const float*)d_in[2];
  const float* chars = (const float*)d_in[3];
  const int* uid = (const int*)d_in[4];
  const int* tok = (const int*)d_in[5];
  const float* W_in = (const float*)d_in[6];
  const float* W_d = (const float*)d_in[7];
  const float* W_invd = (const float*)d_in[8];
  const float* W_vm = (const float*)d_in[9];
  const float* W_sl = (const float*)d_in[10];
  const float* W_sm = (const float*)d_in[11];
  const float* Wp1 = (const float*)d_in[12];
  const float* Wp2 = (const float*)d_in[13];
  const float* Wp3 = (const float*)d_in[14];
  const float* Wq_tok = (const float*)d_in[15];
  const float* Wq = (const float*)d_in[16];
  const float* Wk = (const float*)d_in[17];
  const float* Wv = (const float*)d_in[18];
  const float* Wb = (const float*)d_in[19];
  const float* Wo = (const float*)d_in[20];
  const float* Wt1 = (const float*)d_in[21];
  const float* Wt2 = (const float*)d_in[22];

  float* out = (float*)d_out;
  float* A_I = out;                   // 512*384
  float* Qg = out + 196608;           // 2048*128 (working residual stream)
  float* C_Lo = out + 458752;         // 2048*128
  float* P_out = out + 720896;        // 2048*2048*16

  char* ws = (char*)d_ws;
  float* csl = (float*)(ws + 0);                        // 128 KB
  float* csm = (float*)(ws + 131072);                   // 128 KB
  _Float16* q_hd = (_Float16*)(ws + 262144);            // 512 KB
  _Float16* k_hd = (_Float16*)(ws + 262144 + 524288);   // 512 KB
  _Float16* vT_hd = (_Float16*)(ws + 262144 + 2 * 524288);  // 512 KB
  float* o_buf = (float*)(ws + 262144 + 3 * 524288);    // 1 MB
  _Float16* bias_hp = (_Float16*)(ws + 262144 + 3 * 524288 + 1048576);
  size_t need =
      262144 + 3 * 524288 + 1048576 + (size_t)NBLK * NHEAD * L_ATOMS * L_ATOMS * 2;
  int use_bias = (ws_size >= need) ? 1 : 0;

  k_cl<<<256, 256, 0, stream>>>(pos, charge, elem, chars, W_in, W_sl, W_sm,
                                C_Lo, Qg, csl, csm);
  k_pair<<<dim3(16, 1024), 256, 0, stream>>>(pos, uid, csl, csm, W_d, W_invd,
                                             W_vm, Wp1, Wp2, Wp3, Wb, P_out,
                                             bias_hp, use_bias);
  for (int b = 0; b < NBLK; b++) {
    k_lnqkv<<<256, 256, 0, stream>>>(Qg, Wq + b * 16384, Wk + b * 16384,
                                     Wv + b * 16384, q_hd, k_hd, vT_hd);
    if (use_bias)
      k_attn<1><<<dim3(128, 4), 256, 0, stream>>>(q_hd, k_hd, vT_hd, bias_hp,
                                                  P_out, Wb, o_buf, b);
    else
      k_attn<0><<<dim3(128, 4), 256, 0, stream>>>(q_hd, k_hd, vT_hd, bias_hp,
                                                  P_out, Wb, o_buf, b);
    k_ffn<<<256, 256, 0, stream>>>(Qg, o_buf, Wo + b * 16384, Wt1 + b * 65536,
                                   Wt2 + b * 65536);
  }
  k_token<<<512, 384, 0, stream>>>(Qg, Wq_tok, tok, A_I);
}

// Round 3
// 858.023 us; speedup vs baseline: 2.6068x; 1.0236x over previous
//
#include <hip/hip_runtime.h>
#include <hip/hip_bf16.h>
#include <hip/hip_fp16.h>

#define L_ATOMS 2048
#define N_TOK 512
#define CA 128
#define CP 16
#define CT 384
#define NBLK 3
#define NHEAD 4
#define HDIM 32
#define FFD 512
#define F1D 388

typedef _Float16 half8 __attribute__((ext_vector_type(8)));
typedef _Float16 half4_t __attribute__((ext_vector_type(4)));
typedef float f32x4 __attribute__((ext_vector_type(4)));

__device__ __forceinline__ float grp16_max(float v) {
  v = fmaxf(v, __shfl_xor(v, 1));
  v = fmaxf(v, __shfl_xor(v, 2));
  v = fmaxf(v, __shfl_xor(v, 4));
  v = fmaxf(v, __shfl_xor(v, 8));
  return v;
}
__device__ __forceinline__ float grp16_sum(float v) {
  v += __shfl_xor(v, 1);
  v += __shfl_xor(v, 2);
  v += __shfl_xor(v, 4);
  v += __shfl_xor(v, 8);
  return v;
}

// ---------------------------------------------------------------------------
// C_L = feat @ W_in ; Q init = C_L ; csl = relu(C_L)@W_sl ; csm = relu(C_L)@W_sm
__global__ __launch_bounds__(256) void k_cl(
    const float* __restrict__ pos, const float* __restrict__ charge,
    const float* __restrict__ elem, const float* __restrict__ chars,
    const float* __restrict__ W_in, const float* __restrict__ W_sl,
    const float* __restrict__ W_sm,
    float* __restrict__ out_cl, float* __restrict__ out_q,
    float* __restrict__ csl, float* __restrict__ csm) {
  __shared__ float feat_s[8][F1D];
  __shared__ float rcl_s[8][CA];
  const int t = threadIdx.x;
  const int l0 = blockIdx.x * 8;
  if (t < 24) feat_s[t / 3][t % 3] = pos[l0 * 3 + t];
  else if (t < 32) feat_s[t - 24][3] = charge[l0 + t - 24];
  for (int k = 0; k < 4; k++) {
    int idx = t + k * 256;
    feat_s[idx >> 7][4 + (idx & 127)] = elem[l0 * 128 + idx];
  }
  for (int k = 0; k < 8; k++) {
    int idx = t + k * 256;
    feat_s[idx >> 8][132 + (idx & 255)] = chars[l0 * 256 + idx];
  }
  __syncthreads();
  const int c = t & 127, rh = t >> 7;
  float acc[4] = {0.f, 0.f, 0.f, 0.f};
  for (int f4 = 0; f4 < F1D; f4 += 4) {  // 388 % 4 == 0
    float w0 = W_in[(f4 + 0) * CA + c];
    float w1 = W_in[(f4 + 1) * CA + c];
    float w2 = W_in[(f4 + 2) * CA + c];
    float w3 = W_in[(f4 + 3) * CA + c];
#pragma unroll
    for (int r = 0; r < 4; r++) {
      float4 fv = *(const float4*)&feat_s[rh * 4 + r][f4];
      acc[r] += fv.x * w0 + fv.y * w1 + fv.z * w2 + fv.w * w3;
    }
  }
#pragma unroll
  for (int r = 0; r < 4; r++) {
    int l = l0 + rh * 4 + r;
    out_cl[l * CA + c] = acc[r];
    out_q[l * CA + c] = acc[r];
    rcl_s[rh * 4 + r][c] = fmaxf(acc[r], 0.f);
  }
  __syncthreads();
  const int r = t >> 5, j = t & 15, mat = (t >> 4) & 1;
  const float* W = mat ? W_sm : W_sl;
  float a = 0.f;
  for (int i4 = 0; i4 < CA; i4 += 4) {
    float4 xv = *(const float4*)&rcl_s[r][i4];
    a += xv.x * W[i4 * CP + j] + xv.y * W[(i4 + 1) * CP + j] +
         xv.z * W[(i4 + 2) * CP + j] + xv.w * W[(i4 + 3) * CP + j];
  }
  float* dst = mat ? csm : csl;
  dst[(l0 + r) * CP + j] = a;
}

// ---------------------------------------------------------------------------
// k_pair, MFMA version. Transposed chain: X0=relu(P); X1=relu(W1^T X0);
// X2=relu(W2^T X1); P+=W3^T X2; bias=Wb^T P. All via 16x16x16 f16 MFMA:
// C/D frag (row=quad*4+r, col=lane&15) == B frag (k=quad*4+r, n=lane&15),
// so layers chain in registers. 16 pairs (one l, 16 consecutive m) per
// wave-iteration; block covers 2 l x 256 m.
__global__ __launch_bounds__(256, 4) void k_pair(
    const float* __restrict__ pos, const int* __restrict__ uid,
    const float* __restrict__ csl, const float* __restrict__ csm,
    const float* __restrict__ W_d, const float* __restrict__ W_invd,
    const float* __restrict__ W_vm, const float* __restrict__ Wp1,
    const float* __restrict__ Wp2, const float* __restrict__ Wp3,
    const float* __restrict__ Wb,
    float* __restrict__ P_out, _Float16* __restrict__ bias_hp, int use_bias) {
  __shared__ _Float16 bias_lds[12 * 2 * 256];  // [plane][lrow][m] 12KB
  const int t = threadIdx.x;
  const int w = t >> 6, lane = t & 63;
  const int q = lane >> 4, j16 = lane & 15;
  const int c4 = q * 4;
  const int m_base = blockIdx.x * 256;
  const int l0 = blockIdx.y * 2;
  // weight A-fragments: A[m=j16][k=c4+r]
  half4_t w1f, w2f, w3f, wbf;
#pragma unroll
  for (int r = 0; r < 4; r++) {
    w1f[r] = (_Float16)Wp1[(c4 + r) * 16 + j16];
    w2f[r] = (_Float16)Wp2[(c4 + r) * 16 + j16];
    w3f[r] = (_Float16)Wp3[(c4 + r) * 16 + j16];
  }
  if (j16 < 12) {
    int bb = j16 >> 2, hh = j16 & 3;
#pragma unroll
    for (int r = 0; r < 4; r++)
      wbf[r] = (_Float16)Wb[(bb * 16 + c4 + r) * 4 + hh];
  } else {
    wbf = half4_t{0, 0, 0, 0};
  }
  // geometry weight columns for this lane's 4 channels
  const float4 wdx = *(const float4*)(W_d + c4);
  const float4 wdy = *(const float4*)(W_d + 16 + c4);
  const float4 wdz = *(const float4*)(W_d + 32 + c4);
  const float4 wiv = *(const float4*)(W_invd + c4);
  const float4 wvm = *(const float4*)(W_vm + c4);
  const float4 cl[2] = {*(const float4*)(csl + l0 * 16 + c4),
                        *(const float4*)(csl + (l0 + 1) * 16 + c4)};
  const float plx[2] = {pos[l0 * 3 + 0], pos[(l0 + 1) * 3 + 0]};
  const float ply[2] = {pos[l0 * 3 + 1], pos[(l0 + 1) * 3 + 1]};
  const float plz[2] = {pos[l0 * 3 + 2], pos[(l0 + 1) * 3 + 2]};
  const int uidl[2] = {uid[l0], uid[l0 + 1]};
  const f32x4 z = {0.f, 0.f, 0.f, 0.f};
#pragma unroll
  for (int li = 0; li < 2; li++) {
    const int lg = l0 + li;
#pragma unroll
    for (int it = 0; it < 4; it++) {
      const int m = m_base + w * 64 + it * 16 + j16;
      float pmx = pos[m * 3 + 0], pmy = pos[m * 3 + 1], pmz = pos[m * 3 + 2];
      int um = uid[m];
      float4 cm = *(const float4*)(csm + m * 16 + c4);
      float dx = plx[li] - pmx, dy = ply[li] - pmy, dz = plz[li] - pmz;
      float vfm = (uidl[li] == um) ? 1.f : 0.f;
      float invd_v = vfm / (1.f + sqrtf(dx * dx + dy * dy + dz * dz));
      float dxv = dx * vfm, dyv = dy * vfm, dzv = dz * vfm;
      float pv[4];
      pv[0] = dxv * wdx.x + dyv * wdy.x + dzv * wdz.x + invd_v * wiv.x +
              vfm * wvm.x + cl[li].x + cm.x;
      pv[1] = dxv * wdx.y + dyv * wdy.y + dzv * wdz.y + invd_v * wiv.y +
              vfm * wvm.y + cl[li].y + cm.y;
      pv[2] = dxv * wdx.z + dyv * wdy.z + dzv * wdz.z + invd_v * wiv.z +
              vfm * wvm.z + cl[li].z + cm.z;
      pv[3] = dxv * wdx.w + dyv * wdy.w + dzv * wdz.w + invd_v * wiv.w +
              vfm * wvm.w + cl[li].w + cm.w;
      half4_t b0, b1, b2;
#pragma unroll
      for (int r = 0; r < 4; r++) b0[r] = (_Float16)fmaxf(pv[r], 0.f);
      f32x4 d = __builtin_amdgcn_mfma_f32_16x16x16f16(w1f, b0, z, 0, 0, 0);
#pragma unroll
      for (int r = 0; r < 4; r++) b1[r] = (_Float16)fmaxf(d[r], 0.f);
      d = __builtin_amdgcn_mfma_f32_16x16x16f16(w2f, b1, z, 0, 0, 0);
#pragma unroll
      for (int r = 0; r < 4; r++) b2[r] = (_Float16)fmaxf(d[r], 0.f);
      d = __builtin_amdgcn_mfma_f32_16x16x16f16(w3f, b2, z, 0, 0, 0);
      float pf[4];
#pragma unroll
      for (int r = 0; r < 4; r++) pf[r] = pv[r] + d[r];
      *(float4*)(P_out + ((size_t)lg * L_ATOMS + m) * 16 + c4) =
          make_float4(pf[0], pf[1], pf[2], pf[3]);
      if (use_bias) {
        half4_t bf;
#pragma unroll
        for (int r = 0; r < 4; r++) bf[r] = (_Float16)pf[r];
        f32x4 db = __builtin_amdgcn_mfma_f32_16x16x16f16(wbf, bf, z, 0, 0, 0);
        if (q < 3) {
          int moff = w * 64 + it * 16 + j16;
#pragma unroll
          for (int r = 0; r < 4; r++)
            bias_lds[((q * 4 + r) * 2 + li) * 256 + moff] = (_Float16)db[r];
        }
      }
    }
  }
  if (use_bias) {
    __syncthreads();
    const size_t plane = (size_t)L_ATOMS * L_ATOMS;
#pragma unroll
    for (int kk = 0; kk < 3; kk++) {
      int cid = t + kk * 256;           // 768 chunks of 8 halves
      int pl = cid >> 6;                // 12 planes
      int lrow = (cid >> 5) & 1;
      int chunk = cid & 31;
      half8 v = *(const half8*)&bias_lds[(pl * 2 + lrow) * 256 + chunk * 8];
      *(half8*)(bias_hp + pl * plane + (size_t)(l0 + lrow) * L_ATOMS + m_base +
                chunk * 8) = v;
    }
  }
}

// ---------------------------------------------------------------------------
// x = LN(Q); q/k (head-major fp16), v transposed vT[h][d][l] fp16. 8 rows/block.
__global__ __launch_bounds__(256) void k_lnqkv(
    const float* __restrict__ Qg, const float* __restrict__ Wq,
    const float* __restrict__ Wk, const float* __restrict__ Wv,
    _Float16* __restrict__ q_hd, _Float16* __restrict__ k_hd,
    _Float16* __restrict__ vT_hd) {
  __shared__ float x_s[8][CA];
  const int t = threadIdx.x;
  const int l0 = blockIdx.x * 8;
  ((float4*)x_s)[t] = ((const float4*)(Qg + l0 * CA))[t];
  __syncthreads();
  {
    const int r = t >> 5, i = t & 31;
    float s1 = 0.f, s2 = 0.f;
#pragma unroll
    for (int k = 0; k < 4; k++) {
      float x = x_s[r][i + 32 * k];
      s1 += x;
      s2 += x * x;
    }
#pragma unroll
    for (int m = 1; m <= 16; m <<= 1) {
      s1 += __shfl_xor(s1, m);
      s2 += __shfl_xor(s2, m);
    }
    float mu = s1 * (1.f / 128.f);
    float var = s2 * (1.f / 128.f) - mu * mu;
    float inv = 1.f / sqrtf(var + 1e-5f);
#pragma unroll
    for (int k = 0; k < 4; k++)
      x_s[r][i + 32 * k] = (x_s[r][i + 32 * k] - mu) * inv;
  }
  __syncthreads();
  const int c = t & 127, rh = t >> 7;
  const int h = c >> 5, d = c & 31;
#pragma unroll
  for (int mat = 0; mat < 3; mat++) {
    const float* W = mat == 0 ? Wq : (mat == 1 ? Wk : Wv);
    float acc[4] = {0.f, 0.f, 0.f, 0.f};
    for (int i4 = 0; i4 < CA; i4 += 4) {
      float w0 = W[(i4 + 0) * CA + c];
      float w1 = W[(i4 + 1) * CA + c];
      float w2 = W[(i4 + 2) * CA + c];
      float w3 = W[(i4 + 3) * CA + c];
#pragma unroll
      for (int rr = 0; rr < 4; rr++) {
        float4 xv = *(const float4*)&x_s[rh * 4 + rr][i4];
        acc[rr] += xv.x * w0 + xv.y * w1 + xv.z * w2 + xv.w * w3;
      }
    }
#pragma unroll
    for (int rr = 0; rr < 4; rr++) {
      int l = l0 + rh * 4 + rr;
      if (mat == 0)
        q_hd[(h * L_ATOMS + l) * HDIM + d] = (_Float16)acc[rr];
      else if (mat == 1)
        k_hd[(h * L_ATOMS + l) * HDIM + d] = (_Float16)acc[rr];
      else
        vT_hd[(h * HDIM + d) * L_ATOMS + l] = (_Float16)acc[rr];
    }
  }
}

// ---------------------------------------------------------------------------
// flash attention, one (16-row l-tile, head) per block; 4 waves split m-range.
template <int USE_BIAS>
__global__ __launch_bounds__(256) void k_attn(
    const _Float16* __restrict__ q_hd, const _Float16* __restrict__ k_hd,
    const _Float16* __restrict__ vT_hd, const _Float16* __restrict__ bias_hp,
    const float* __restrict__ Pmat, const float* __restrict__ Wb,
    float* __restrict__ o_buf, int b) {
  __shared__ __align__(16) _Float16 p_lds[4][16][40];
  __shared__ float o_sh[4][16][33];
  __shared__ float M_sh[4][16];
  __shared__ float S_sh[4][16];
  __shared__ float wb_s[16];
  const int t = threadIdx.x;
  const int w = t >> 6, lane = t & 63;
  const int l0 = blockIdx.x * 16;
  const int h = blockIdx.y;
  if (USE_BIAS == 0 && t < 16) wb_s[t] = Wb[(b * 16 + t) * 4 + h];
  __syncthreads();
  const int c16 = lane & 15, q4 = lane >> 4;
  half8 qa = *(const half8*)(q_hd + ((h * L_ATOMS + l0 + c16) * HDIM + q4 * 8));
  f32x4 o0 = {0.f, 0.f, 0.f, 0.f}, o1 = {0.f, 0.f, 0.f, 0.f};
  float M[4] = {-INFINITY, -INFINITY, -INFINITY, -INFINITY};
  float S[4] = {0.f, 0.f, 0.f, 0.f};
  const float scale = 0.17677669529663687f;  // 1/sqrt(32)
  for (int it = 0; it < 16; it++) {
    const int m0 = w * 512 + it * 32;
    half8 kb0 =
        *(const half8*)(k_hd + ((h * L_ATOMS + m0 + c16) * HDIM + q4 * 8));
    half8 kb1 =
        *(const half8*)(k_hd + ((h * L_ATOMS + m0 + 16 + c16) * HDIM + q4 * 8));
    f32x4 z = {0.f, 0.f, 0.f, 0.f};
    f32x4 c0 = __builtin_amdgcn_mfma_f32_16x16x32_f16(qa, kb0, z, 0, 0, 0);
    f32x4 c1 = __builtin_amdgcn_mfma_f32_16x16x32_f16(qa, kb1, z, 0, 0, 0);
    float l0v[4], l1v[4];
#pragma unroll
    for (int r = 0; r < 4; r++) {
      float b0, b1;
      if (USE_BIAS) {
        const _Float16* bp =
            bias_hp + ((size_t)(b * 4 + h) * L_ATOMS + (l0 + q4 * 4 + r)) *
                          L_ATOMS +
            m0 + c16;
        b0 = (float)bp[0];
        b1 = (float)bp[16];
      } else {
        const float* Pp0 =
            Pmat + ((size_t)(l0 + q4 * 4 + r) * L_ATOMS + m0 + c16) * 16;
        const float* Pp1 = Pp0 + 16 * 16;
        float a0 = 0.f, a1 = 0.f;
#pragma unroll
        for (int c2 = 0; c2 < 16; c2++) {
          a0 += Pp0[c2] * wb_s[c2];
          a1 += Pp1[c2] * wb_s[c2];
        }
        b0 = a0;
        b1 = a1;
      }
      l0v[r] = c0[r] * scale + b0;
      l1v[r] = c1[r] * scale + b1;
    }
#pragma unroll
    for (int r = 0; r < 4; r++) {
      float tm = grp16_max(fmaxf(l0v[r], l1v[r]));
      float Mn = fmaxf(M[r], tm);
      float al = __expf(M[r] - Mn);
      float p0 = __expf(l0v[r] - Mn);
      float p1 = __expf(l1v[r] - Mn);
      float rs = grp16_sum(p0 + p1);
      S[r] = S[r] * al + rs;
      M[r] = Mn;
      o0[r] *= al;
      o1[r] *= al;
      p_lds[w][q4 * 4 + r][c16] = (_Float16)p0;
      p_lds[w][q4 * 4 + r][16 + c16] = (_Float16)p1;
    }
    __syncthreads();
    half8 pa = *(const half8*)(&p_lds[w][c16][q4 * 8]);
    half8 vb0 =
        *(const half8*)(vT_hd + ((h * HDIM + c16) * L_ATOMS + m0 + q4 * 8));
    half8 vb1 = *(const half8*)(vT_hd +
                                ((h * HDIM + 16 + c16) * L_ATOMS + m0 + q4 * 8));
    o0 = __builtin_amdgcn_mfma_f32_16x16x32_f16(pa, vb0, o0, 0, 0, 0);
    o1 = __builtin_amdgcn_mfma_f32_16x16x32_f16(pa, vb1, o1, 0, 0, 0);
    __syncthreads();
  }
#pragma unroll
  for (int r = 0; r < 4; r++) {
    o_sh[w][q4 * 4 + r][c16] = o0[r];
    o_sh[w][q4 * 4 + r][16 + c16] = o1[r];
  }
  if (c16 == 0) {
#pragma unroll
    for (int r = 0; r < 4; r++) {
      M_sh[w][q4 * 4 + r] = M[r];
      S_sh[w][q4 * 4 + r] = S[r];
    }
  }
  __syncthreads();
  {
    const int d = t & 31, r8 = t >> 5;
#pragma unroll
    for (int k = 0; k < 2; k++) {
      int row = r8 + 8 * k;
      float Mg = fmaxf(fmaxf(M_sh[0][row], M_sh[1][row]),
                       fmaxf(M_sh[2][row], M_sh[3][row]));
      float Sg = 0.f, ov = 0.f;
#pragma unroll
      for (int ww = 0; ww < 4; ww++) {
        float e = __expf(M_sh[ww][row] - Mg);
        Sg += S_sh[ww][row] * e;
        ov += o_sh[ww][row][d] * e;
      }
      o_buf[(l0 + row) * CA + h * HDIM + d] = ov / Sg;
    }
  }
}

// ---------------------------------------------------------------------------
// Q += o@Wo ; y = LN(Q) ; Q += relu(y@Wt1)@Wt2.  8 rows/block.
__global__ __launch_bounds__(256) void k_ffn(
    float* __restrict__ Qg, const float* __restrict__ o_buf,
    const float* __restrict__ Wo, const float* __restrict__ Wt1,
    const float* __restrict__ Wt2) {
  __shared__ float o_s[8][CA];
  __shared__ float q_s[8][CA];
  __shared__ float h_s[8][FFD];
  const int t = threadIdx.x;
  const int l0 = blockIdx.x * 8;
  ((float4*)o_s)[t] = ((const float4*)(o_buf + l0 * CA))[t];
  ((float4*)q_s)[t] = ((const float4*)(Qg + l0 * CA))[t];
  __syncthreads();
  const int c = t & 127, rh = t >> 7;
  {
    float acc[4] = {0.f, 0.f, 0.f, 0.f};
    for (int i4 = 0; i4 < CA; i4 += 4) {
      float w0 = Wo[(i4 + 0) * CA + c];
      float w1 = Wo[(i4 + 1) * CA + c];
      float w2 = Wo[(i4 + 2) * CA + c];
      float w3 = Wo[(i4 + 3) * CA + c];
#pragma unroll
      for (int r = 0; r < 4; r++) {
        float4 ov = *(const float4*)&o_s[rh * 4 + r][i4];
        acc[r] += ov.x * w0 + ov.y * w1 + ov.z * w2 + ov.w * w3;
      }
    }
#pragma unroll
    for (int r = 0; r < 4; r++) q_s[rh * 4 + r][c] += acc[r];
  }
  __syncthreads();
  {
    const int r = t >> 5, i = t & 31;
    float s1 = 0.f, s2 = 0.f;
#pragma unroll
    for (int k = 0; k < 4; k++) {
      float x = q_s[r][i + 32 * k];
      s1 += x;
      s2 += x * x;
    }
#pragma unroll
    for (int m = 1; m <= 16; m <<= 1) {
      s1 += __shfl_xor(s1, m);
      s2 += __shfl_xor(s2, m);
    }
    float mu = s1 * (1.f / 128.f);
    float var = s2 * (1.f / 128.f) - mu * mu;
    float inv = 1.f / sqrtf(var + 1e-5f);
#pragma unroll
    for (int k = 0; k < 4; k++)
      o_s[r][i + 32 * k] = (q_s[r][i + 32 * k] - mu) * inv;
  }
  __syncthreads();
  {
    float a1[8], a2[8];
#pragma unroll
    for (int r = 0; r < 8; r++) {
      a1[r] = 0.f;
      a2[r] = 0.f;
    }
    for (int i4 = 0; i4 < CA; i4 += 4) {
      float w1v[4], w2v[4];
#pragma unroll
      for (int qq = 0; qq < 4; qq++) {
        w1v[qq] = Wt1[(i4 + qq) * FFD + t];
        w2v[qq] = Wt1[(i4 + qq) * FFD + 256 + t];
      }
#pragma unroll
      for (int r = 0; r < 8; r++) {
        float4 yv = *(const float4*)&o_s[r][i4];
        a1[r] += yv.x * w1v[0] + yv.y * w1v[1] + yv.z * w1v[2] + yv.w * w1v[3];
        a2[r] += yv.x * w2v[0] + yv.y * w2v[1] + yv.z * w2v[2] + yv.w * w2v[3];
      }
    }
#pragma unroll
    for (int r = 0; r < 8; r++) {
      h_s[r][t] = fmaxf(a1[r], 0.f);
      h_s[r][256 + t] = fmaxf(a2[r], 0.f);
    }
  }
  __syncthreads();
  {
    float acc[4] = {0.f, 0.f, 0.f, 0.f};
    for (int j4 = 0; j4 < FFD; j4 += 4) {
      float w0 = Wt2[(j4 + 0) * CA + c];
      float w1 = Wt2[(j4 + 1) * CA + c];
      float w2 = Wt2[(j4 + 2) * CA + c];
      float w3 = Wt2[(j4 + 3) * CA + c];
#pragma unroll
      for (int r = 0; r < 4; r++) {
        float4 hv = *(const float4*)&h_s[rh * 4 + r][j4];
        acc[r] += hv.x * w0 + hv.y * w1 + hv.z * w2 + hv.w * w3;
      }
    }
#pragma unroll
    for (int r = 0; r < 4; r++) {
      int l = l0 + rh * 4 + r;
      Qg[l * CA + c] = q_s[rh * 4 + r][c] + acc[r];
    }
  }
}

// ---------------------------------------------------------------------------
// pQ = relu(Q @ Wq_tok) via 16x16x32 f16 MFMA. grid (24 col-tiles, 32),
// 4 waves/block, each wave one 16x16 tile, K=128 in 4 chunks.
__global__ __launch_bounds__(256) void k_tok_mm(
    const float* __restrict__ Qg, const float* __restrict__ Wq_tok,
    float* __restrict__ pQ) {
  const int t = threadIdx.x;
  const int w = t >> 6, lane = t & 63;
  const int q = lane >> 4, j16 = lane & 15;
  const int c0 = blockIdx.x * 16;
  const int r0 = (blockIdx.y * 4 + w) * 16;
  f32x4 acc = {0.f, 0.f, 0.f, 0.f};
#pragma unroll
  for (int kk = 0; kk < 4; kk++) {
    // A frag: Q rows, fp32 -> fp16
    const float* ap = Qg + (r0 + j16) * CA + kk * 32 + q * 8;
    float4 a0 = *(const float4*)ap;
    float4 a1 = *(const float4*)(ap + 4);
    half8 af = {(_Float16)a0.x, (_Float16)a0.y, (_Float16)a0.z, (_Float16)a0.w,
                (_Float16)a1.x, (_Float16)a1.y, (_Float16)a1.z, (_Float16)a1.w};
    // B frag: Wq_tok[k][n], column reads
    half8 bf;
#pragma unroll
    for (int jj = 0; jj < 8; jj++)
      bf[jj] = (_Float16)Wq_tok[(kk * 32 + q * 8 + jj) * CT + c0 + j16];
    acc = __builtin_amdgcn_mfma_f32_16x16x32_f16(af, bf, acc, 0, 0, 0);
  }
#pragma unroll
  for (int r = 0; r < 4; r++)
    pQ[(r0 + q * 4 + r) * CT + c0 + j16] = fmaxf(acc[r], 0.f);
}

// ---------------------------------------------------------------------------
// A_I[i] = mean over atoms of pQ rows (already relu'd). Sorted map.
__global__ __launch_bounds__(384) void k_tok_mean(
    const float* __restrict__ pQ, const int* __restrict__ tok,
    float* __restrict__ A_I) {
  __shared__ int lo_s, hi_s;
  const int i = blockIdx.x;
  const int t = threadIdx.x;
  if (t == 0) {
    int lo = 0, hi = L_ATOMS;
    while (lo < hi) {
      int mid = (lo + hi) >> 1;
      if (tok[mid] < i) lo = mid + 1; else hi = mid;
    }
    lo_s = lo;
    int lo2 = lo, hi2 = L_ATOMS;
    while (lo2 < hi2) {
      int mid = (lo2 + hi2) >> 1;
      if (tok[mid] < i + 1) lo2 = mid + 1; else hi2 = mid;
    }
    hi_s = lo2;
  }
  __syncthreads();
  const int lo = lo_s, hi = hi_s;
  float acc = 0.f;
  for (int a = lo; a < hi; a++) acc += pQ[a * CT + t];
  int cnt = hi - lo;
  A_I[i * CT + t] = cnt > 0 ? acc / (float)cnt : 0.f;
}

// ---------------------------------------------------------------------------
extern "C" void kernel_launch(void* const* d_in, const int* in_sizes, int n_in,
                              void* d_out, int out_size, void* d_ws,
                              size_t ws_size, hipStream_t stream) {
  const float* pos = (const float*)d_in[0];
  const float* charge = (const float*)d_in[1];
  const float* elem = (const float*)d_in[2];
  const float* chars = (const float*)d_in[3];
  const int* uid = (const int*)d_in[4];
  const int* tok = (const int*)d_in[5];
  const float* W_in = (const float*)d_in[6];
  const float* W_d = (const float*)d_in[7];
  const float* W_invd = (const float*)d_in[8];
  const float* W_vm = (const float*)d_in[9];
  const float* W_sl = (const float*)d_in[10];
  const float* W_sm = (const float*)d_in[11];
  const float* Wp1 = (const float*)d_in[12];
  const float* Wp2 = (const float*)d_in[13];
  const float* Wp3 = (const float*)d_in[14];
  const float* Wq_tok = (const float*)d_in[15];
  const float* Wq = (const float*)d_in[16];
  const float* Wk = (const float*)d_in[17];
  const float* Wv = (const float*)d_in[18];
  const float* Wb = (const float*)d_in[19];
  const float* Wo = (const float*)d_in[20];
  const float* Wt1 = (const float*)d_in[21];
  const float* Wt2 = (const float*)d_in[22];

  float* out = (float*)d_out;
  float* A_I = out;                   // 512*384
  float* Qg = out + 196608;           // 2048*128 (working residual stream)
  float* C_Lo = out + 458752;         // 2048*128
  float* P_out = out + 720896;        // 2048*2048*16

  char* ws = (char*)d_ws;
  float* csl = (float*)(ws + 0);                        // 128 KB
  float* csm = (float*)(ws + 131072);                   // 128 KB
  _Float16* q_hd = (_Float16*)(ws + 262144);            // 512 KB
  _Float16* k_hd = (_Float16*)(ws + 262144 + 524288);   // 512 KB
  _Float16* vT_hd = (_Float16*)(ws + 262144 + 2 * 524288);  // 512 KB
  float* o_buf = (float*)(ws + 262144 + 3 * 524288);    // 1 MB
  _Float16* bias_hp = (_Float16*)(ws + 262144 + 3 * 524288 + 1048576);
  // pQ (3 MB) reuses the csl..o_buf region, all dead after the last k_ffn.
  float* pQ = (float*)(ws + 0);
  size_t need =
      262144 + 3 * 524288 + 1048576 + (size_t)NBLK * NHEAD * L_ATOMS * L_ATOMS * 2;
  int use_bias = (ws_size >= need) ? 1 : 0;

  k_cl<<<256, 256, 0, stream>>>(pos, charge, elem, chars, W_in, W_sl, W_sm,
                                C_Lo, Qg, csl, csm);
  k_pair<<<dim3(8, 1024), 256, 0, stream>>>(pos, uid, csl, csm, W_d, W_invd,
                                            W_vm, Wp1, Wp2, Wp3, Wb, P_out,
                                            bias_hp, use_bias);
  for (int b = 0; b < NBLK; b++) {
    k_lnqkv<<<256, 256, 0, stream>>>(Qg, Wq + b * 16384, Wk + b * 16384,
                                     Wv + b * 16384, q_hd, k_hd, vT_hd);
    if (use_bias)
      k_attn<1><<<dim3(128, 4), 256, 0, stream>>>(q_hd, k_hd, vT_hd, bias_hp,
                                                  P_out, Wb, o_buf, b);
    else
      k_attn<0><<<dim3(128, 4), 256, 0, stream>>>(q_hd, k_hd, vT_hd, bias_hp,
                                                  P_out, Wb, o_buf, b);
    k_ffn<<<256, 256, 0, stream>>>(Qg, o_buf, Wo + b * 16384, Wt1 + b * 65536,
                                   Wt2 + b * 65536);
  }
  k_tok_mm<<<dim3(24, 32), 256, 0, stream>>>(Qg, Wq_tok, pQ);
  k_tok_mean<<<512, 384, 0, stream>>>(pQ, tok, A_I);
}